// Round 10
// baseline (66.347 us; speedup 1.0000x reference)
//
#include <hip/hip_runtime.h>
#include <stdint.h>

#define NCLS 80
#define BGI 80
#define BB 16
#define NGT 32
#define MM 33600
#define EPSF 1e-9f
#define CAP 1024
#define NPAIR 512
#define NZB 700
#define ZPB 15360  // float4 per zero block: 700*15360 == 10752000 == B*M*80/4

// IoU exactly mirroring reference pairwise_iou op order; no FMA contraction.
__device__ __forceinline__ float iou_f(const float4 b1, const float4 b2) {
#pragma clang fp contract(off)
  float ltx = fmaxf(b1.x, b2.x);
  float lty = fmaxf(b1.y, b2.y);
  float rbx = fminf(b1.z, b2.z);
  float rby = fminf(b1.w, b2.w);
  float iw = fmaxf(rbx - ltx, 0.0f);
  float ih = fmaxf(rby - lty, 0.0f);
  float inter = iw * ih;
  float a1 = (b1.z - b1.x) * (b1.w - b1.y);
  float a2 = (b2.z - b2.x) * (b2.w - b2.y);
  return inter / (a1 + a2 - inter + EPSF);
}

// P0: precompute anchor centers (same op order as reference anchor_points)
// and zero the packed (cnt|g-sum) scatter array. 2100*256 == 537600 exact.
__global__ __launch_bounds__(256) void k_prep(
    const float4* __restrict__ anchors, float2* __restrict__ centers,
    unsigned int* __restrict__ pk) {
#pragma clang fp contract(off)
  const int i = blockIdx.x * 256 + threadIdx.x;
  if (i < MM) {
    const float4 ab = anchors[i];
    centers[i] = make_float2((ab.x + ab.z) * 0.5f, (ab.y + ab.w) * 0.5f);
  }
  pk[i] = 0u;
}

// K1 hybrid grid: blocks [0,512) = per-(b,g) top-k (8 waves each, 2/CU);
// blocks [512,1212) = pure score-zeroing (fills the CU's remaining 16 waves,
// so the 172MB store drain overlaps the latency-bound scans on other waves —
// no shared vmcnt queue, no barrier-drain interaction).
//
// Top-k = bound-then-rank (63.8us-proven structure), 512 threads:
//  pass1: per-thread min of SQUARED dist -> 16 HALF-WAVE (32-lane) minima;
//         wave 0: T = sqrt(9th smallest) — valid bound (the 9 smallest
//         partition-minima are 9 distinct elements <= T, so K9 <= T);
//         monotone sqrt commutes with min/rank.
//  pass2: dist = sqrt(d2) (reference rounding); collect keys
//         (distbits<<32|idx), dist<=T, into LDS.
//  rank:  rank = #smaller keys; keys unique via idx low bits -> exact top-9
//         with lax.top_k tie semantics (equal dist -> smaller index).
__global__ __launch_bounds__(512) void k_topk(
    const float4* __restrict__ anchors, const float2* __restrict__ centers,
    const float4* __restrict__ gtb, const float* __restrict__ maskgt,
    unsigned int* __restrict__ pk, float4* __restrict__ zscores) {
#pragma clang fp contract(off)
  const int tid = threadIdx.x;

  if (blockIdx.x >= NPAIR) {  // ---- zero-writer block
    const int zb = blockIdx.x - NPAIR;
    float4* z = zscores + (size_t)zb * ZPB;
    const float4 zero4 = make_float4(0.f, 0.f, 0.f, 0.f);
#pragma unroll
    for (int it = 0; it < 30; ++it)  // 30*512 == 15360 exact
      z[it * 512 + tid] = zero4;
    return;
  }

  const int pair = blockIdx.x;            // b*32+g
  if (maskgt[pair] == 0.0f) return;       // masked gt contributes nothing
  const int b = pair >> 5;
  const int g = pair & 31;
  const int lane = tid & 63;
  const int wid = tid >> 6;               // 0..7
  const int half = tid >> 5;              // 0..15 (32-lane partition id)
  const float4 gb = gtb[pair];
  const float gcx = (gb.x + gb.z) * 0.5f;
  const float gcy = (gb.y + gb.w) * 0.5f;

  __shared__ unsigned long long buf[CAP];
  __shared__ unsigned long long winners[27];
  __shared__ float s_wmin[16];
  __shared__ float s_T;
  __shared__ unsigned int s_cnt;

  const int LSTART[3] = {0, 25600, 32000};
  const int LLEN[3]   = {25600, 6400, 1600};

#pragma unroll
  for (int lev = 0; lev < 3; ++lev) {
    const int start = LSTART[lev];
    const int len = LLEN[lev];

    // pass 1: branch-free per-thread min of squared distance (no sqrt)
    float mymin = 3.4e38f;
    for (int j = tid; j < len; j += 512) {
      const float2 ac = centers[start + j];
      const float dx = gcx - ac.x;
      const float dy = gcy - ac.y;
      mymin = fminf(mymin, dx * dx + dy * dy);
    }
    // reduce within each 32-lane half (xor masks <32 stay in-half)
#pragma unroll
    for (int s = 16; s >= 1; s >>= 1)
      mymin = fminf(mymin, __shfl_xor(mymin, s, 64));
    if ((lane & 31) == 0) s_wmin[half] = mymin;
    if (tid == 0) s_cnt = 0u;
    __syncthreads();

    // T = sqrt(9th smallest of the 16 squared partition minima), wave 0 only
    if (wid == 0 && lane < 16) {
      const float v = s_wmin[lane];
      int r = 0;
#pragma unroll
      for (int q = 0; q < 16; ++q) {
        const float o = s_wmin[q];
        r += (o < v) || (o == v && q < lane);
      }
      if (r == 8) s_T = sqrtf(v);  // unique rank -> exactly one lane
    }
    __syncthreads();
    const float T = s_T;

    // pass 2: collect candidates with sqrt'd dist (reference rounding)
    for (int j = tid; j < len; j += 512) {
      const float2 ac = centers[start + j];
      const float dx = gcx - ac.x;
      const float dy = gcy - ac.y;
      const float dist = sqrtf(dx * dx + dy * dy);
      if (dist <= T) {
        const unsigned int p = atomicAdd(&s_cnt, 1u);
        if (p < CAP)
          buf[p] = ((unsigned long long)__float_as_uint(dist) << 32) |
                   (unsigned long long)(unsigned int)(start + j);
      }
    }
    __syncthreads();

    const int m = (int)min(s_cnt, (unsigned int)CAP);
    // rank-select: exactly 9 winners (keys unique -> ranks unique)
    for (int i = tid; i < m; i += 512) {
      const unsigned long long k = buf[i];
      int r = 0;
      for (int q = 0; q < m; ++q) r += (buf[q] < k);
      if (r < 9) winners[lev * 9 + r] = k;
    }
    __syncthreads();
  }

  if (wid != 0) return;  // wave 0 finishes; no more barriers

  unsigned int mycand = 0;
  if (lane < 27) mycand = (unsigned int)(winners[lane] & 0xffffffffu);

  // candidate IoUs + inside-gt test (lanes 0..26)
  float ov = 0.0f;
  bool inside = false;
  if (lane < 27) {
    const float4 ab = anchors[mycand];
    ov = iou_f(gb, ab);
    const float2 ac = centers[mycand];
    const float m1 = fminf(fminf(ac.x - gb.x, ac.y - gb.y),
                           fminf(gb.z - ac.x, gb.w - ac.y));
    inside = m1 > EPSF;
  }
  // thr = mean + std(ddof=1) over the 27 gathered IoUs
  float s = (lane < 27) ? ov : 0.0f;
#pragma unroll
  for (int sft = 32; sft >= 1; sft >>= 1) s += __shfl_xor(s, sft, 64);
  const float mean = s / 27.0f;
  float dev = (lane < 27) ? (ov - mean) : 0.0f;
  float s2 = dev * dev;
#pragma unroll
  for (int sft = 32; sft >= 1; sft >>= 1) s2 += __shfl_xor(s2, sft, 64);
  const float thr = mean + sqrtf(s2 / 26.0f);

  if (lane < 27 && inside && ov > thr) {
    // packed: cnt in bits[31:20], sum of g in bits[19:0].
    // <=32 adds: cnt<=32, g-sum<=992 -> no field overflow; cnt==1 -> low=g.
    atomicAdd(&pk[b * MM + (int)mycand], (1u << 20) | (unsigned int)g);
  }
}

// B1 sparse: per (b,a) resolve assignment; write labels/bbox/fg and — since
// the score tensor is pre-zeroed by k_topk's zero blocks — ONE scalar score
// per fg anchor.
__global__ __launch_bounds__(256) void k_out(
    const float4* __restrict__ anchors, const float4* __restrict__ gtb,
    const int* __restrict__ glabels, const float4* __restrict__ predb,
    const unsigned int* __restrict__ pk,
    float* __restrict__ out_labels, float4* __restrict__ out_bbox,
    float* __restrict__ out_fg, float* __restrict__ out_scores) {
  const int a = blockIdx.x * 256 + threadIdx.x;
  if (a >= MM) return;
  const int b = blockIdx.y;
  const int i = b * MM + a;
  const unsigned int p = pk[i];
  const unsigned int c = p >> 20;
  int g = 0;
  const bool fg = (c != 0u);
  if (c == 1u) {
    g = (int)(p & 0xFFFFFu);
  } else if (c > 1u) {
    // reference: column replaced by one_hot(argmax_g overlaps) — includes
    // masked gts; first-max tie-break like jnp.argmax.
    const float4 ab = anchors[a];
    float best = -1.0f;
    for (int gg = 0; gg < NGT; ++gg) {
      const float ovv = iou_f(gtb[b * NGT + gg], ab);
      if (ovv > best) { best = ovv; g = gg; }
    }
  }
  const int lbl = fg ? glabels[b * NGT + g] : BGI;
  out_labels[i] = (float)lbl;
  out_bbox[i] = gtb[b * NGT + g];  // !fg -> g==0 (argmax of zeros)
  out_fg[i] = fg ? 1.0f : 0.0f;
  if (fg) {
    const float io = iou_f(gtb[b * NGT + g], predb[i]);
    out_scores[(size_t)i * NCLS + lbl] = io;  // rest of row stays zero
  }
}

extern "C" void kernel_launch(void* const* d_in, const int* in_sizes, int n_in,
                              void* d_out, int out_size, void* d_ws, size_t ws_size,
                              hipStream_t stream) {
  // Identify inputs by size (robust to how the n_level tuple is passed).
  const float* anchors = nullptr;
  const float* gtb = nullptr;
  const int* glab = nullptr;
  const float* maskgt = nullptr;
  const float* predb = nullptr;
  int seen512 = 0;
  for (int i = 0; i < n_in; ++i) {
    const int sz = in_sizes[i];
    if (sz == 134400 && !anchors) anchors = (const float*)d_in[i];
    else if (sz == 2048 && !gtb) gtb = (const float*)d_in[i];
    else if (sz == 512) {
      if (seen512++ == 0) glab = (const int*)d_in[i];
      else maskgt = (const float*)d_in[i];
    } else if (sz == 2150400 && !predb) predb = (const float*)d_in[i];
  }
  if (!anchors || !gtb || !glab || !maskgt || !predb) return;  // defensive

  float* out = (float*)d_out;
  float* out_labels = out;                          // [B*M]
  float4* out_bbox = (float4*)(out + 537600);       // [B*M][4]
  float* out_scores = out + 2688000;                // [B*M][80]
  float* out_fg = out + 45696000;                   // [B*M]

  unsigned int* pk = (unsigned int*)d_ws;           // [B*M] packed cnt|gsum
  float2* centers = (float2*)(pk + 537600);         // [M], 8B-aligned

  k_prep<<<dim3(2100), dim3(256), 0, stream>>>(
      (const float4*)anchors, centers, pk);

  k_topk<<<dim3(NPAIR + NZB), dim3(512), 0, stream>>>(
      (const float4*)anchors, centers, (const float4*)gtb, maskgt, pk,
      (float4*)out_scores);

  k_out<<<dim3(132, BB), dim3(256), 0, stream>>>(
      (const float4*)anchors, (const float4*)gtb, glab, (const float4*)predb,
      pk, out_labels, out_bbox, out_fg, out_scores);
}